// Round 1
// baseline (3561.169 us; speedup 1.0000x reference)
//
#include <hip/hip_runtime.h>
#include <math.h>

// Problem constants (B,L,E,H,D) = (8,1024,1024,16,64)
constexpr int Bc = 8;
constexpr int Lc = 1024;
constexpr int Ec = 1024;
constexpr int Hc = 16;
constexpr int Dc = 64;
constexpr float EPSc = 1e-5f;

// ---------------------------------------------------------------------------
// GEMM: C[M][N] = sum_k A[M][K] * B[N][K] + bias[N]   (both A and B K-contiguous)
// 128x128 tile, 256 threads, 8x8 micro-tile per thread, K-tile 16.
// grid.x = M tiles (consecutive blocks share the B panel for L2 locality)
// ---------------------------------------------------------------------------
__global__ __launch_bounds__(256)
void gemm_nt(const float* __restrict__ A, const float* __restrict__ Bm,
             const float* __restrict__ bias, float* __restrict__ C,
             int M, int N, int K) {
    constexpr int TILE = 128;
    constexpr int KT = 16;
    __shared__ float As[KT][TILE];   // [k][m]
    __shared__ float Bs[KT][TILE];   // [k][n]

    const int tid = threadIdx.x;
    const int bm = blockIdx.x * TILE;
    const int bn = blockIdx.y * TILE;
    const int tx = tid & 15;         // n micro-tile index
    const int ty = tid >> 4;         // m micro-tile index

    float acc[8][8];
#pragma unroll
    for (int i = 0; i < 8; ++i)
#pragma unroll
        for (int j = 0; j < 8; ++j) acc[i][j] = 0.f;

    const int lr = tid >> 1;           // row within tile (0..127)
    const int lk = (tid & 1) * 8;      // k offset (0 or 8)
    const float* aptr = A + (size_t)(bm + lr) * K + lk;
    const float* bptr = Bm + (size_t)(bn + lr) * K + lk;

    for (int k0 = 0; k0 < K; k0 += KT) {
        float4 a0 = *(const float4*)(aptr + k0);
        float4 a1 = *(const float4*)(aptr + k0 + 4);
        float4 b0 = *(const float4*)(bptr + k0);
        float4 b1 = *(const float4*)(bptr + k0 + 4);
        __syncthreads();   // previous iteration's LDS reads complete
        As[lk + 0][lr] = a0.x; As[lk + 1][lr] = a0.y; As[lk + 2][lr] = a0.z; As[lk + 3][lr] = a0.w;
        As[lk + 4][lr] = a1.x; As[lk + 5][lr] = a1.y; As[lk + 6][lr] = a1.z; As[lk + 7][lr] = a1.w;
        Bs[lk + 0][lr] = b0.x; Bs[lk + 1][lr] = b0.y; Bs[lk + 2][lr] = b0.z; Bs[lk + 3][lr] = b0.w;
        Bs[lk + 4][lr] = b1.x; Bs[lk + 5][lr] = b1.y; Bs[lk + 6][lr] = b1.z; Bs[lk + 7][lr] = b1.w;
        __syncthreads();
#pragma unroll
        for (int k = 0; k < KT; ++k) {
            float4 av0 = *(const float4*)&As[k][ty * 8];
            float4 av1 = *(const float4*)&As[k][ty * 8 + 4];
            float4 bv0 = *(const float4*)&Bs[k][tx * 8];
            float4 bv1 = *(const float4*)&Bs[k][tx * 8 + 4];
            float av[8] = {av0.x, av0.y, av0.z, av0.w, av1.x, av1.y, av1.z, av1.w};
            float bv[8] = {bv0.x, bv0.y, bv0.z, bv0.w, bv1.x, bv1.y, bv1.z, bv1.w};
#pragma unroll
            for (int i = 0; i < 8; ++i)
#pragma unroll
                for (int j = 0; j < 8; ++j) acc[i][j] += av[i] * bv[j];
        }
    }

    // epilogue: add bias, store
    const int col = bn + tx * 8;
    float4 bias0 = *(const float4*)(bias + col);
    float4 bias1 = *(const float4*)(bias + col + 4);
#pragma unroll
    for (int i = 0; i < 8; ++i) {
        size_t row = (size_t)(bm + ty * 8 + i);
        float4 c0 = {acc[i][0] + bias0.x, acc[i][1] + bias0.y, acc[i][2] + bias0.z, acc[i][3] + bias0.w};
        float4 c1 = {acc[i][4] + bias1.x, acc[i][5] + bias1.y, acc[i][6] + bias1.z, acc[i][7] + bias1.w};
        *(float4*)(C + row * N + col) = c0;
        *(float4*)(C + row * N + col + 4) = c1;
    }
}

// ---------------------------------------------------------------------------
// Attention: one block per (b, h, 8-query tile). Scores row-block in LDS,
// K/V staged in 128-row tiles. Also accumulates avg_attn (head+query mean).
// qkv layout: [b][l][3E], q at e=h*64+d, k at E+h*64+d, v at 2E+h*64+d.
// ---------------------------------------------------------------------------
constexpr int TQ = 8;
constexpr int TK = 128;
constexpr int KPAD = 68;   // 64 + 4 pad to spread LDS banks

__global__ __launch_bounds__(256)
void attn_kernel(const float* __restrict__ qkv, float* __restrict__ ctx,
                 float* __restrict__ avg_out) {
    __shared__ float Qs[TQ][Dc];       // 2 KB
    __shared__ float Ss[TQ][Lc];       // 32 KB
    __shared__ float KVs[TK][KPAD];    // 34 KB

    const int tid = threadIdx.x;
    const int qt = blockIdx.x;     // query tile 0..127
    const int h  = blockIdx.y;
    const int b  = blockIdx.z;
    const int l0 = qt * TQ;
    const size_t rowstride = 3 * Ec;
    const float* base = qkv + (size_t)b * Lc * rowstride + (size_t)h * Dc;

    // load Q tile (scaled by 1/sqrt(D) = 0.125)
    {
        int q = tid >> 5;            // 0..7
        int d = (tid & 31) * 2;      // 0..62
        const float* p = base + (size_t)(l0 + q) * rowstride + d;
        Qs[q][d]     = p[0] * 0.125f;
        Qs[q][d + 1] = p[1] * 0.125f;
    }

    // ---- phase A: scores = Q K^T ----
    const int kk = tid & 127;          // key within tile
    const int qg = (tid >> 7) * 4;     // query group base: 0 or 4
    for (int kt = 0; kt < Lc / TK; ++kt) {
        __syncthreads();   // protect KVs (and initial Qs writes)
        {
            int r = tid >> 1, hf = (tid & 1) * 32;
            const float* src = base + (size_t)(kt * TK + r) * rowstride + Ec + hf;
#pragma unroll
            for (int j = 0; j < 8; ++j)
                *(float4*)&KVs[r][hf + j * 4] = *(const float4*)(src + j * 4);
        }
        __syncthreads();
        float s0 = 0.f, s1 = 0.f, s2 = 0.f, s3 = 0.f;
#pragma unroll
        for (int d0 = 0; d0 < Dc; d0 += 4) {
            float4 kv = *(const float4*)&KVs[kk][d0];
            float4 q0 = *(const float4*)&Qs[qg + 0][d0];
            float4 q1 = *(const float4*)&Qs[qg + 1][d0];
            float4 q2 = *(const float4*)&Qs[qg + 2][d0];
            float4 q3 = *(const float4*)&Qs[qg + 3][d0];
            s0 += q0.x * kv.x + q0.y * kv.y + q0.z * kv.z + q0.w * kv.w;
            s1 += q1.x * kv.x + q1.y * kv.y + q1.z * kv.z + q1.w * kv.w;
            s2 += q2.x * kv.x + q2.y * kv.y + q2.z * kv.z + q2.w * kv.w;
            s3 += q3.x * kv.x + q3.y * kv.y + q3.z * kv.z + q3.w * kv.w;
        }
        Ss[qg + 0][kt * TK + kk] = s0;
        Ss[qg + 1][kt * TK + kk] = s1;
        Ss[qg + 2][kt * TK + kk] = s2;
        Ss[qg + 3][kt * TK + kk] = s3;
    }
    __syncthreads();

    // ---- softmax: 4 waves x 2 rows each ----
    {
        const int wave = tid >> 6, lane = tid & 63;
#pragma unroll
        for (int rr = 0; rr < 2; ++rr) {
            int q = wave * 2 + rr;
            float m = -1e30f;
            for (int j = lane; j < Lc; j += 64) m = fmaxf(m, Ss[q][j]);
#pragma unroll
            for (int off = 32; off; off >>= 1) m = fmaxf(m, __shfl_xor(m, off));
            float sum = 0.f;
            for (int j = lane; j < Lc; j += 64) {
                float e = __expf(Ss[q][j] - m);
                Ss[q][j] = e;
                sum += e;
            }
#pragma unroll
            for (int off = 32; off; off >>= 1) sum += __shfl_xor(sum, off);
            float inv = 1.f / sum;
            for (int j = lane; j < Lc; j += 64) Ss[q][j] *= inv;
        }
    }
    __syncthreads();

    // ---- avg_attn accumulation: sum over the 8 query rows, one atomic per key ----
    for (int m = tid; m < Lc; m += 256) {
        float s = 0.f;
#pragma unroll
        for (int q = 0; q < TQ; ++q) s += Ss[q][m];
        atomicAdd(&avg_out[b * Lc + m], s * (1.0f / (Hc * Lc)));
    }

    // ---- phase B: ctx = W V ----
    const int d4 = (tid & 15) * 4;      // 0..60
    const int qq = (tid >> 4) & 7;      // 0..7
    const int mh = tid >> 7;            // m-split half: 0 or 1
    float4 acc = {0.f, 0.f, 0.f, 0.f};
    for (int kt = 0; kt < Lc / TK; ++kt) {
        __syncthreads();
        {
            int r = tid >> 1, hf = (tid & 1) * 32;
            const float* src = base + (size_t)(kt * TK + r) * rowstride + 2 * Ec + hf;
#pragma unroll
            for (int j = 0; j < 8; ++j)
                *(float4*)&KVs[r][hf + j * 4] = *(const float4*)(src + j * 4);
        }
        __syncthreads();
        const int mbase = kt * TK + mh * 64;
        const int rbase = mh * 64;
#pragma unroll 8
        for (int mm = 0; mm < 64; ++mm) {
            float w = Ss[qq][mbase + mm];
            float4 v = *(const float4*)&KVs[rbase + mm][d4];
            acc.x += w * v.x; acc.y += w * v.y; acc.z += w * v.z; acc.w += w * v.w;
        }
    }
    __syncthreads();
    if (mh == 1) *(float4*)&Ss[0][(tid & 127) * 4] = acc;
    __syncthreads();
    if (mh == 0) {
        float4 other = *(const float4*)&Ss[0][(tid & 127) * 4];
        acc.x += other.x; acc.y += other.y; acc.z += other.z; acc.w += other.w;
        float* dst = ctx + (size_t)(b * Lc + l0 + qq) * Ec + h * Dc + d4;
        *(float4*)dst = acc;
    }
}

// ---------------------------------------------------------------------------
// LayerNorm stats: one block per (b,l) row. h = x + attn_out.
// ---------------------------------------------------------------------------
__global__ __launch_bounds__(256)
void stats_kernel(const float* __restrict__ x, const float* __restrict__ attn_out,
                  float2* __restrict__ stats) {
    const int row = blockIdx.x;
    const int tid = threadIdx.x;
    const float* xp = x + (size_t)row * Ec;
    const float* ap = attn_out + (size_t)row * Ec;
    float4 xv = *(const float4*)(xp + tid * 4);
    float4 av = *(const float4*)(ap + tid * 4);
    float h0 = xv.x + av.x, h1 = xv.y + av.y, h2 = xv.z + av.z, h3 = xv.w + av.w;
    float s = h0 + h1 + h2 + h3;
    float ss = h0 * h0 + h1 * h1 + h2 * h2 + h3 * h3;
#pragma unroll
    for (int off = 32; off; off >>= 1) {
        s += __shfl_xor(s, off);
        ss += __shfl_xor(ss, off);
    }
    __shared__ float wsum[4], wsq[4];
    const int wave = tid >> 6, lane = tid & 63;
    if (lane == 0) { wsum[wave] = s; wsq[wave] = ss; }
    __syncthreads();
    if (tid == 0) {
        float ts = wsum[0] + wsum[1] + wsum[2] + wsum[3];
        float tq = wsq[0] + wsq[1] + wsq[2] + wsq[3];
        float mean = ts * (1.0f / Ec);
        float var = tq * (1.0f / Ec) - mean * mean;
        stats[row] = make_float2(mean, rsqrtf(var + EPSc));
    }
}

// ---------------------------------------------------------------------------
// Pooled output: pooled[b][f] = mean_l( (h-mu)*rstd*gamma[f] + beta[f] )
// grid: (16 l-chunks, 4 f-chunks, 8 b); atomicAdd into zeroed d_out.
// ---------------------------------------------------------------------------
__global__ __launch_bounds__(256)
void pool_kernel(const float* __restrict__ x, const float* __restrict__ attn_out,
                 const float2* __restrict__ stats, const float* __restrict__ gamma,
                 const float* __restrict__ beta, float* __restrict__ pooled) {
    const int b = blockIdx.z;
    const int f = blockIdx.y * 256 + threadIdx.x;
    const int l0 = blockIdx.x * 64;
    const float g = gamma[f];
    const float be = beta[f];
    float acc = 0.f;
    for (int l = l0; l < l0 + 64; ++l) {
        size_t idx = (size_t)(b * Lc + l) * Ec + f;
        float2 st = stats[b * Lc + l];
        float h = x[idx] + attn_out[idx];
        acc += (h - st.x) * st.y * g + be;
    }
    atomicAdd(&pooled[b * Ec + f], acc * (1.0f / Lc));
}

// ---------------------------------------------------------------------------
extern "C" void kernel_launch(void* const* d_in, const int* in_sizes, int n_in,
                              void* d_out, int out_size, void* d_ws, size_t ws_size,
                              hipStream_t stream) {
    const float* x      = (const float*)d_in[0];   // (B,L,E)
    const float* w_qkv  = (const float*)d_in[1];   // (3E,E)
    const float* b_qkv  = (const float*)d_in[2];   // (3E,)
    const float* w_out  = (const float*)d_in[3];   // (E,E)
    const float* b_out  = (const float*)d_in[4];   // (E,)
    const float* gamma  = (const float*)d_in[5];   // (E,)
    const float* beta   = (const float*)d_in[6];   // (E,)
    float* out = (float*)d_out;                    // pooled (B,E) then avg_attn (B,L)

    // workspace layout (floats): qkv 25165824 | ctx 8388608 | stats 16384
    float* qkv   = (float*)d_ws;
    float* ctx   = qkv + (size_t)Bc * Lc * 3 * Ec;
    float* stats = ctx + (size_t)Bc * Lc * Ec;
    float* attn_out = qkv;   // reuse: qkv dead after attention

    const int M = Bc * Lc;   // 8192

    hipMemsetAsync(d_out, 0, (size_t)out_size * sizeof(float), stream);

    // 1) QKV projection: (8192 x 1024) x (3072 x 1024)^T
    dim3 g1(M / 128, (3 * Ec) / 128);
    gemm_nt<<<g1, 256, 0, stream>>>(x, w_qkv, b_qkv, qkv, M, 3 * Ec, Ec);

    // 2) attention + avg_attn
    dim3 g2(Lc / TQ, Hc, Bc);
    attn_kernel<<<g2, 256, 0, stream>>>(qkv, ctx, out + Bc * Ec);

    // 3) output projection: (8192 x 1024) x (1024 x 1024)^T  (writes over qkv)
    dim3 g3(M / 128, Ec / 128);
    gemm_nt<<<g3, 256, 0, stream>>>(ctx, w_out, b_out, attn_out, M, Ec, Ec);

    // 4) LN stats
    stats_kernel<<<M, 256, 0, stream>>>(x, attn_out, (float2*)stats);

    // 5) pooled
    dim3 g5(16, 4, Bc);
    pool_kernel<<<g5, 256, 0, stream>>>(x, attn_out, (float2*)stats, gamma, beta, out);
}